// Round 9
// baseline (189.263 us; speedup 1.0000x reference)
//
#include <hip/hip_runtime.h>
#include <hip/hip_bf16.h>

#define S_LEN 8192
#define D_MODEL 512
#define NH 8
#define HD 64
#define WIN 256
#define NB 2

// Q projection scale folds 1/sqrt(HD) AND log2(e) so attention softmax can
// use native exp2 (v_exp_f32) with no per-element multiply.
#define QSCALE 0.1803368801111204f   // 0.125 * log2(e)

// bare v_exp_f32 (2^x). libm exp2f adds a denormal-fixup sequence (~3x the
// VALU ops) -- that was round 2's regression.
#define EXP2N(x) __builtin_amdgcn_exp2f(x)

typedef __hip_bfloat16 bf16;
typedef __attribute__((ext_vector_type(8))) short short8;
typedef __attribute__((ext_vector_type(4))) float f32x4;

static __device__ __forceinline__ short f2bf(float f) {
    bf16 h = __float2bfloat16(f);
    return *reinterpret_cast<short*>(&h);
}

static __device__ __forceinline__ void gload_lds16(short* lds, const short* g) {
    __builtin_amdgcn_global_load_lds(
        (const __attribute__((address_space(1))) void*)g,
        (__attribute__((address_space(3))) void*)lds, 16, 0, 0);
}

// ---------------------------------------------------------------------------
// W (fp32 [k][n]) -> wT (bf16 [n][k]) for the 3 weights (blockIdx.z).
// The ONLY prep kernel now: round-9 fuses x's conversion into proj itself,
// removing the convert_x launch (4 -> 3 kernels; ~10-15 us/launch boundary
// in this harness per cross-round accounting).
// ---------------------------------------------------------------------------
__global__ __launch_bounds__(256) void convert_wT_kernel(
    const float* __restrict__ Wq, const float* __restrict__ Wk,
    const float* __restrict__ Wv, short* __restrict__ wT)
{
    __shared__ float t[32][33];
    const float* W = blockIdx.z == 0 ? Wq : (blockIdx.z == 1 ? Wk : Wv);
    const int n0 = blockIdx.x * 32, k0 = blockIdx.y * 32;
    const int tx = threadIdx.x & 31, ty = threadIdx.x >> 5;
#pragma unroll
    for (int i = 0; i < 4; ++i)
        t[ty + 8 * i][tx] = W[(size_t)(k0 + ty + 8 * i) * D_MODEL + n0 + tx];
    __syncthreads();
#pragma unroll
    for (int i = 0; i < 4; ++i) {
        const int nl = ty + 8 * i, kl = tx;
        wT[(size_t)blockIdx.z * D_MODEL * D_MODEL +
           (size_t)(n0 + nl) * D_MODEL + k0 + kl] = f2bf(t[kl][nl]);
    }
}

// ---------------------------------------------------------------------------
// bf16 MFMA projection GEMM with FUSED x conversion: C = bf16(x) @ wT^T.
// q,k stored head-major [bh][s][d]; v stored TRANSPOSED [bh][d][s].
// A-staging (T14 async-split, replaces the xb workspace + convert_x kernel):
//   issue 8 float4 loads of fp32 x BEFORE the MFMA phase -> the vmcnt wait
//   lands after compute -> convert to bf16 -> 4x ds_write_b128 into the
//   same swizzled LDS layout -> barrier. HBM/L2 latency hides under MFMA
//   exactly as the DMA did. B-staging keeps global_load_lds from wT.
// Occupancy: +32 VGPR (ar[8]) -> 2 waves/SIMD, but the 64 KB LDS already
// caps at 2 blocks/CU, so the binding constraint is unchanged.
// ---------------------------------------------------------------------------
__global__ __launch_bounds__(256) void proj_mfma_kernel(
    const float* __restrict__ x, const short* __restrict__ wT,
    const float* __restrict__ bq, const float* __restrict__ bk,
    const float* __restrict__ bv, bf16* __restrict__ qkv)
{
    __shared__ short Ash[2][128 * 64];
    __shared__ short Bsh[2][128 * 64];

    // --- XCD-aware bijective remap (nwg = 12*128 = 1536, 1536 % 8 == 0) ---
    const int nwg  = gridDim.x * gridDim.y;          // 1536
    const int orig = blockIdx.y * gridDim.x + blockIdx.x;
    const int wid  = (orig & 7) * (nwg >> 3) + (orig >> 3);
    const int bx   = wid % 12;
    const int by   = wid / 12;

    const int widx = bx >> 2;
    const int col0 = (bx & 3) * 128;
    const int row0 = by * 128;
    const int tid  = threadIdx.x;
    const int w    = tid >> 6;
    const int lane = tid & 63;
    const int col  = lane & 15;
    const int kg   = lane >> 4;

    const float* bias = widx == 0 ? bq : (widx == 1 ? bk : bv);
    const float scale = widx == 0 ? QSCALE : 1.0f;
    const short* wbase = wT + (size_t)widx * D_MODEL * D_MODEL;

    const f32x4 zero4 = {0.f, 0.f, 0.f, 0.f};
    f32x4 acc[4][4];
#pragma unroll
    for (int i = 0; i < 4; ++i)
#pragma unroll
        for (int j = 0; j < 4; ++j) acc[i][j] = zero4;

    const int wm0 = (w >> 1) * 64;
    const int wn0 = (w & 1) * 64;

    // B staging: 4 x global_load_lds(16B) per thread per K-step, XOR swizzle.
    auto stageB = [&](int buf, int kb) {
#pragma unroll
        for (int ci = 0; ci < 4; ++ci) {
            const int Lb = w * 256 + ci * 64;        // wave-uniform LDS chunk
            const int L  = Lb + lane;
            const int mm = L >> 3;
            const int kc = ((L & 7) - (mm >> 1)) & 7;
            gload_lds16(&Bsh[buf][Lb * 8],
                        wbase + (size_t)(col0 + mm) * D_MODEL + kb + kc * 8);
        }
    };

    // A staging part 1: issue fp32 loads of x into registers (no wait here).
    float4 ar[8];
    auto loadA = [&](int kb) {
#pragma unroll
        for (int ci = 0; ci < 4; ++ci) {
            const int L  = w * 256 + ci * 64 + lane;
            const int mm = L >> 3;
            const int kc = ((L & 7) - (mm >> 1)) & 7;
            const float* src = x + (size_t)(row0 + mm) * D_MODEL + kb + kc * 8;
            ar[2 * ci]     = *(const float4*)(src);
            ar[2 * ci + 1] = *(const float4*)(src + 4);
        }
    };

    // A staging part 2: convert + ds_write (placed AFTER compute so the
    // vmcnt wait for ar[] hides under the MFMA phase).
    auto writeA = [&](int buf) {
#pragma unroll
        for (int ci = 0; ci < 4; ++ci) {
            const int L = w * 256 + ci * 64 + lane;
            short8 s;
            s[0] = f2bf(ar[2 * ci].x);     s[1] = f2bf(ar[2 * ci].y);
            s[2] = f2bf(ar[2 * ci].z);     s[3] = f2bf(ar[2 * ci].w);
            s[4] = f2bf(ar[2 * ci + 1].x); s[5] = f2bf(ar[2 * ci + 1].y);
            s[6] = f2bf(ar[2 * ci + 1].z); s[7] = f2bf(ar[2 * ci + 1].w);
            *(short8*)(&Ash[buf][(size_t)L * 8]) = s;
        }
    };

    // prologue: stage K-step 0 into buffer 0 (no compute to hide under)
    loadA(0);
    stageB(0, 0);
    writeA(0);

    const int NSTEP = D_MODEL / 64;                  // 8
    for (int it = 0; it < NSTEP; ++it) {
        __syncthreads();   // drains buf[it&1]'s DMA + ds_writes; also orders
                           // prev compute of buf[(it+1)&1] before overwrite

        const int nb = (it + 1) & 1;
        if (it + 1 < NSTEP) {
            stageB(nb, (it + 1) * 64);
            loadA((it + 1) * 64);
        }

        const short* Ab = Ash[it & 1];
        const short* Bb = Bsh[it & 1];

#pragma unroll
        for (int s = 0; s < 2; ++s) {
            short8 af[4], bfr[4];
#pragma unroll
            for (int mt = 0; mt < 4; ++mt) {
                const int m = wm0 + mt * 16 + col;
                const int c = m * 8 + ((s * 4 + kg + (m >> 1)) & 7);
                af[mt] = *(const short8*)(Ab + (size_t)c * 8);
            }
#pragma unroll
            for (int nt = 0; nt < 4; ++nt) {
                const int n = wn0 + nt * 16 + col;
                const int c = n * 8 + ((s * 4 + kg + (n >> 1)) & 7);
                bfr[nt] = *(const short8*)(Bb + (size_t)c * 8);
            }
#pragma unroll
            for (int mt = 0; mt < 4; ++mt)
#pragma unroll
                for (int nt = 0; nt < 4; ++nt)
                    acc[mt][nt] = __builtin_amdgcn_mfma_f32_16x16x32_bf16(
                        af[mt], bfr[nt], acc[mt][nt], 0, 0, 0);
        }

        if (it + 1 < NSTEP) writeA(nb);   // vmcnt wait lands here, post-MFMA
        // no trailing barrier: next iteration's top barrier covers reuse
    }

    bf16* dst = qkv + (size_t)widx * (NB * NH * S_LEN * HD);
#pragma unroll
    for (int nt = 0; nt < 4; ++nt) {
        const int n = col0 + wn0 + nt * 16 + col;
        const float bias_v = bias[n];
        const int h = n >> 6, d = n & 63;
#pragma unroll
        for (int mt = 0; mt < 4; ++mt) {
            const int m0 = row0 + wm0 + mt * 16 + kg * 4;
            const int b = m0 >> 13, s0 = m0 & (S_LEN - 1);
            if (widx == 2) {
                short4 pk;
                pk.x = f2bf(acc[mt][nt][0] + bias_v);
                pk.y = f2bf(acc[mt][nt][1] + bias_v);
                pk.z = f2bf(acc[mt][nt][2] + bias_v);
                pk.w = f2bf(acc[mt][nt][3] + bias_v);
                *(short4*)&dst[(((size_t)(b * NH + h)) * HD + d) * S_LEN + s0] = pk;
            } else {
#pragma unroll
                for (int r = 0; r < 4; ++r)
                    dst[(((size_t)(b * NH + h)) * S_LEN + s0 + r) * HD + d] =
                        __float2bfloat16((acc[mt][nt][r] + bias_v) * scale);
            }
        }
    }
}

// ---------------------------------------------------------------------------
// Fallback fp32 projection (only if ws too small)
// ---------------------------------------------------------------------------
__global__ __launch_bounds__(256) void proj_kernel(
    const float* __restrict__ x, const float* __restrict__ Wm,
    const float* __restrict__ bias, bf16* __restrict__ dst, float scale,
    int transpose_v)
{
    __shared__ float As[16][64];
    __shared__ float Bs[16][64];
    const int tid  = threadIdx.x;
    const int row0 = blockIdx.y * 64;
    const int col0 = blockIdx.x * 64;
    const int ty = tid >> 4, tx = tid & 15;
    const int t4 = tid * 4;
    const int ai = t4 >> 4, aj = t4 & 15;
    const int bj = t4 >> 6, bi = t4 & 63;
    float acc[4][4] = {};
    for (int kb = 0; kb < D_MODEL; kb += 16) {
        float4 av = *(const float4*)(x  + (size_t)(row0 + ai) * D_MODEL + kb + aj);
        float4 bv = *(const float4*)(Wm + (size_t)(kb + bj)  * D_MODEL + col0 + bi);
        As[aj + 0][ai] = av.x; As[aj + 1][ai] = av.y;
        As[aj + 2][ai] = av.z; As[aj + 3][ai] = av.w;
        *(float4*)(&Bs[bj][bi]) = bv;
        __syncthreads();
#pragma unroll
        for (int k = 0; k < 16; ++k) {
            float a[4], b[4];
#pragma unroll
            for (int ii = 0; ii < 4; ++ii) a[ii] = As[k][ty * 4 + ii];
#pragma unroll
            for (int jj = 0; jj < 4; ++jj) b[jj] = Bs[k][tx * 4 + jj];
#pragma unroll
            for (int ii = 0; ii < 4; ++ii)
#pragma unroll
                for (int jj = 0; jj < 4; ++jj) acc[ii][jj] += a[ii] * b[jj];
        }
        __syncthreads();
    }
#pragma unroll
    for (int ii = 0; ii < 4; ++ii) {
        const int m = row0 + ty * 4 + ii;
        const int b = m >> 13, s = m & (S_LEN - 1);
#pragma unroll
        for (int jj = 0; jj < 4; ++jj) {
            const int n = col0 + tx * 4 + jj;
            const int h = n >> 6, d = n & 63;
            const float v = (acc[ii][jj] + bias[n]) * scale;
            if (transpose_v)
                dst[(((size_t)(b * NH + h)) * HD + d) * S_LEN + s] = __float2bfloat16(v);
            else
                dst[(((size_t)(b * NH + h)) * S_LEN + s) * HD + d] = __float2bfloat16(v);
        }
    }
}

// ---------------------------------------------------------------------------
// Flash sliding-window attention v12 (r8 verbatim -- best measured: ~50 us.
// Psh round-trip + 16x16x32 PV; native exp2; defer-max; tree reductions).
// ---------------------------------------------------------------------------
__global__ __launch_bounds__(512) void attn_mfma5_kernel(
    const bf16* __restrict__ qw, const bf16* __restrict__ kw,
    const bf16* __restrict__ vt, float* __restrict__ out)
{
    __shared__ __align__(16) short Ksh[2][4096];     // [key][d] swizzled, 2x8KB
    __shared__ __align__(16) short Vsh[2][4096];     // [d][key] swizzled, 2x8KB
    __shared__ __align__(16) short Psh[8][16][72];   // per-wave [q][key], 18.4KB

    // --- XCD-aware bijective remap (nwg = 16*64 = 1024, 1024 % 8 == 0) ---
    const int orig = blockIdx.y * gridDim.x + blockIdx.x;
    const int wf   = (orig & 7) * 128 + (orig >> 3);
    const int bh   = wf >> 6;
    const int qt0  = (wf & 63) * 128;

    const int tid  = threadIdx.x;
    const int w    = tid >> 6;              // 0..7
    const int lane = tid & 63;
    const int col  = lane & 15;
    const int kg   = lane >> 4;
    const int q0   = qt0 + w * 16;
    const int q    = q0 + col;
    const size_t base = (size_t)bh * S_LEN * HD;

    const short* qg  = (const short*)qw;
    const short* kgp = (const short*)kw;
    const short* vgp = (const short*)vt;

    const int kt_lo = qt0 - WIN < 0 ? 0 : qt0 - WIN;
    const int kt_hi0 = qt0 + WIN + 64;      // covers q up to qt0+127
    const int kt_hi = kt_hi0 > S_LEN - 64 ? S_LEN - 64 : kt_hi0;
    const int NT    = ((kt_hi - kt_lo) >> 6) + 1;

    // staging: 512 chunks per array per tile, 1 per thread, XOR swizzle
    const int r0 = tid >> 3, c0 = (tid & 7) ^ (r0 & 7);
    const int ldsb = w * 64 * 8;            // wave-uniform chunk base (shorts)

    // Q B-frag: B[n=q][k=d]
    const short* qptr = qg + base + (size_t)q * HD + kg * 8;
    const short8 qB0 = *(const short8*)(qptr);
    const short8 qB1 = *(const short8*)(qptr + 32);

    const f32x4 zero4 = {0.f, 0.f, 0.f, 0.f};
    f32x4 Oacc[4] = {zero4, zero4, zero4, zero4};
    float m = -1e30f, l = 0.f;

    const int x7 = col & 7;

    // prologue: stage tile 0 into buffer 0
    gload_lds16(&Ksh[0][ldsb], kgp + base + (size_t)(kt_lo + r0) * HD + c0 * 8);
    gload_lds16(&Vsh[0][ldsb], vgp + base + (size_t)r0 * S_LEN + kt_lo + c0 * 8);

    for (int i = 0; i < NT; ++i) {
        __syncthreads();   // drains tile i's DMA (issued previous iteration)

        if (i + 1 < NT) {  // issue DMA for tile i+1 -> overlaps compute below
            const int ktn = kt_lo + 64 * (i + 1);
            const int nb = (i + 1) & 1;
            gload_lds16(&Ksh[nb][ldsb], kgp + base + (size_t)(ktn + r0) * HD + c0 * 8);
            gload_lds16(&Vsh[nb][ldsb], vgp + base + (size_t)r0 * S_LEN + ktn + c0 * 8);
        }

        const int kt = kt_lo + 64 * i;
        const short* Kb = Ksh[i & 1];
        const short* Vb = Vsh[i & 1];

        // ---- S^T = K . Q^T : A[m=key][k=d] from swizzled LDS ----
        f32x4 sc[4];
        __builtin_amdgcn_s_setprio(1);
#pragma unroll
        for (int t = 0; t < 4; ++t) {
            const int key = 16 * t + col;
            const short8 kA0 = *(const short8*)(Kb + (size_t)(key * 8 + (kg ^ x7)) * 8);
            const short8 kA1 = *(const short8*)(Kb + (size_t)(key * 8 + ((kg + 4) ^ x7)) * 8);
            f32x4 a = zero4;
            a = __builtin_amdgcn_mfma_f32_16x16x32_bf16(kA0, qB0, a, 0, 0, 0);
            a = __builtin_amdgcn_mfma_f32_16x16x32_bf16(kA1, qB1, a, 0, 0, 0);
            sc[t] = a;                     // sc[t][r] = S[kt+16t+4kg+r][q] (log2 units)
        }
        __builtin_amdgcn_s_setprio(0);

        // per-wave masking: tile fully valid iff kt >= q0+15-WIN && kt+63 <= q0+WIN
        const bool need_mask = (kt < q0 + 15 - WIN) || (kt + 63 > q0 + WIN);
        if (need_mask) {
#pragma unroll
            for (int t = 0; t < 4; ++t)
#pragma unroll
                for (int r = 0; r < 4; ++r) {
                    const int j = kt + 16 * t + kg * 4 + r;
                    if (j < q - WIN || j > q + WIN) sc[t][r] = -1e30f;
                }
        }

        // ---- tile max (tree) + cross-kg reduce ----
        float tm0 = fmaxf(fmaxf(sc[0][0], sc[0][1]), fmaxf(sc[0][2], sc[0][3]));
        float tm1 = fmaxf(fmaxf(sc[1][0], sc[1][1]), fmaxf(sc[1][2], sc[1][3]));
        float tm2 = fmaxf(fmaxf(sc[2][0], sc[2][1]), fmaxf(sc[2][2], sc[2][3]));
        float tm3 = fmaxf(fmaxf(sc[3][0], sc[3][1]), fmaxf(sc[3][2], sc[3][3]));
        float tmax = fmaxf(fmaxf(tm0, tm1), fmaxf(tm2, tm3));
        tmax = fmaxf(tmax, __shfl_xor(tmax, 16));
        tmax = fmaxf(tmax, __shfl_xor(tmax, 32));

        // ---- T13 defer-max: rescale only if some column grew by >8 ----
        if (__any(tmax > m + 8.f)) {
            const float mnew = fmaxf(m, tmax);
            const float alpha = EXP2N(m - mnew);   // 0 on first tile (m=-1e30)
            m = mnew;
#pragma unroll
            for (int dt = 0; dt < 4; ++dt)
#pragma unroll
                for (int r = 0; r < 4; ++r) Oacc[dt][r] *= alpha;
            l *= alpha;
        }

        // ---- p = 2^(sc - m); masked entries (-1e30) underflow to 0 ----
        float p[4][4];
#pragma unroll
        for (int t = 0; t < 4; ++t)
#pragma unroll
            for (int r = 0; r < 4; ++r) p[t][r] = EXP2N(sc[t][r] - m);

        float r0s = (p[0][0] + p[0][1]) + (p[0][2] + p[0][3]);
        float r1s = (p[1][0] + p[1][1]) + (p[1][2] + p[1][3]);
        float r2s = (p[2][0] + p[2][1]) + (p[2][2] + p[2][3]);
        float r3s = (p[3][0] + p[3][1]) + (p[3][2] + p[3][3]);
        float rs = (r0s + r1s) + (r2s + r3s);
        rs += __shfl_xor(rs, 16);
        rs += __shfl_xor(rs, 32);
        l += rs;

        // ---- P -> per-wave LDS (4x b64), read back as B-frags ----
#pragma unroll
        for (int t = 0; t < 4; ++t) {
            short4 pk;
            pk.x = f2bf(p[t][0]); pk.y = f2bf(p[t][1]);
            pk.z = f2bf(p[t][2]); pk.w = f2bf(p[t][3]);
            *(short4*)&Psh[w][col][16 * t + 4 * kg] = pk;
        }

        const short* pp = &Psh[w][col][kg * 8];   // same-wave RAW: in-order DS
        const short8 pB0 = *(const short8*)(pp);
        const short8 pB1 = *(const short8*)(pp + 32);

        // ---- O^T += V^T . P^T : A[m=d][k=key] from swizzled LDS ----
        __builtin_amdgcn_s_setprio(1);
#pragma unroll
        for (int dt = 0; dt < 4; ++dt) {
            const int d = dt * 16 + col;
            const short8 vA0 = *(const short8*)(Vb + (size_t)(d * 8 + (kg ^ x7)) * 8);
            const short8 vA1 = *(const short8*)(Vb + (size_t)(d * 8 + ((kg + 4) ^ x7)) * 8);
            Oacc[dt] = __builtin_amdgcn_mfma_f32_16x16x32_bf16(vA0, pB0, Oacc[dt], 0, 0, 0);
            Oacc[dt] = __builtin_amdgcn_mfma_f32_16x16x32_bf16(vA1, pB1, Oacc[dt], 0, 0, 0);
        }
        __builtin_amdgcn_s_setprio(0);
    }

    // ---- epilogue: coalesced float4 stores ----
    const float inv = 1.0f / l;
    const int b = bh >> 3, h = bh & 7;
    float* op = out + ((size_t)(b * S_LEN + q)) * D_MODEL + h * HD + kg * 4;
#pragma unroll
    for (int dt = 0; dt < 4; ++dt) {
        float4 o;
        o.x = Oacc[dt][0] * inv; o.y = Oacc[dt][1] * inv;
        o.z = Oacc[dt][2] * inv; o.w = Oacc[dt][3] * inv;
        *(float4*)(op + dt * 16) = o;
    }
}

// ---------------------------------------------------------------------------
extern "C" void kernel_launch(void* const* d_in, const int* in_sizes, int n_in,
                              void* d_out, int out_size, void* d_ws, size_t ws_size,
                              hipStream_t stream)
{
    const float* x  = (const float*)d_in[0];
    const float* Wq = (const float*)d_in[1];
    const float* bq = (const float*)d_in[2];
    const float* Wk = (const float*)d_in[3];
    const float* bk = (const float*)d_in[4];
    const float* Wv = (const float*)d_in[5];
    const float* bv = (const float*)d_in[6];
    float* out = (float*)d_out;

    const size_t n_elem = (size_t)NB * NH * S_LEN * HD;
    bf16* qw = (bf16*)d_ws;
    bf16* kw = qw + n_elem;
    bf16* vw = kw + n_elem;        // v TRANSPOSED: [bh][d][s]
    short* wT = (short*)(vw + n_elem);

    const size_t need = (3 * n_elem + 3 * (size_t)D_MODEL * D_MODEL) * sizeof(short);

    if (ws_size >= need) {
        dim3 wgrid(D_MODEL / 32, D_MODEL / 32, 3);
        convert_wT_kernel<<<wgrid, 256, 0, stream>>>(Wq, Wk, Wv, wT);
        dim3 ggrid(12, (NB * S_LEN) / 128);
        proj_mfma_kernel<<<ggrid, 256, 0, stream>>>(x, wT, bq, bk, bv, qw);
    } else {
        dim3 pgrid(D_MODEL / 64, (NB * S_LEN) / 64);
        proj_kernel<<<pgrid, 256, 0, stream>>>(x, Wq, bq, qw, QSCALE, 0);
        proj_kernel<<<pgrid, 256, 0, stream>>>(x, Wk, bk, kw, 1.0f, 0);
        proj_kernel<<<pgrid, 256, 0, stream>>>(x, Wv, bv, vw, 1.0f, 1);
    }

    dim3 agrid(NB * NH, S_LEN / 128);
    attn_mfma5_kernel<<<agrid, 512, 0, stream>>>(qw, kw, vw, out);
}

// Round 10
// 176.508 us; speedup vs baseline: 1.0723x; 1.0723x over previous
//
#include <hip/hip_runtime.h>
#include <hip/hip_bf16.h>

#define S_LEN 8192
#define D_MODEL 512
#define NH 8
#define HD 64
#define WIN 256
#define NB 2

// Q projection scale folds 1/sqrt(HD) AND log2(e) so attention softmax can
// use native exp2 (v_exp_f32) with no per-element multiply.
#define QSCALE 0.1803368801111204f   // 0.125 * log2(e)

// bare v_exp_f32 (2^x). libm exp2f adds a denormal-fixup sequence (~3x the
// VALU ops) -- that was round 2's regression.
#define EXP2N(x) __builtin_amdgcn_exp2f(x)

typedef __hip_bfloat16 bf16;
typedef __attribute__((ext_vector_type(8))) short short8;
typedef __attribute__((ext_vector_type(4))) float f32x4;

static __device__ __forceinline__ short f2bf(float f) {
    bf16 h = __float2bfloat16(f);
    return *reinterpret_cast<short*>(&h);
}

static __device__ __forceinline__ void gload_lds16(short* lds, const short* g) {
    __builtin_amdgcn_global_load_lds(
        (const __attribute__((address_space(1))) void*)g,
        (__attribute__((address_space(3))) void*)lds, 16, 0, 0);
}

// ---------------------------------------------------------------------------
// x (fp32 [16384][512]) -> xb (bf16), flat convert. RESTORED (round-9
// post-mortem: the launch-count theory is falsified -- the ~65 us harness
// gap is fixed regardless of kernel count; fusing conversion into proj only
// made proj slower. Separate BW-bound convert is the right structure.)
// ---------------------------------------------------------------------------
__global__ __launch_bounds__(256) void convert_x_kernel(
    const float* __restrict__ x, short* __restrict__ xb)
{
    const int n4 = (NB * S_LEN * D_MODEL) / 4;
    for (int i = blockIdx.x * 256 + threadIdx.x; i < n4; i += gridDim.x * 256) {
        float4 v = ((const float4*)x)[i];
        short4 o;
        o.x = f2bf(v.x); o.y = f2bf(v.y); o.z = f2bf(v.z); o.w = f2bf(v.w);
        ((short4*)xb)[i] = o;
    }
}

// ---------------------------------------------------------------------------
// W (fp32 [k][n]) -> wT (bf16 [n][k]) for the 3 weights (blockIdx.z)
// ---------------------------------------------------------------------------
__global__ __launch_bounds__(256) void convert_wT_kernel(
    const float* __restrict__ Wq, const float* __restrict__ Wk,
    const float* __restrict__ Wv, short* __restrict__ wT)
{
    __shared__ float t[32][33];
    const float* W = blockIdx.z == 0 ? Wq : (blockIdx.z == 1 ? Wk : Wv);
    const int n0 = blockIdx.x * 32, k0 = blockIdx.y * 32;
    const int tx = threadIdx.x & 31, ty = threadIdx.x >> 5;
#pragma unroll
    for (int i = 0; i < 4; ++i)
        t[ty + 8 * i][tx] = W[(size_t)(k0 + ty + 8 * i) * D_MODEL + n0 + tx];
    __syncthreads();
#pragma unroll
    for (int i = 0; i < 4; ++i) {
        const int nl = ty + 8 * i, kl = tx;
        wT[(size_t)blockIdx.z * D_MODEL * D_MODEL +
           (size_t)(n0 + nl) * D_MODEL + k0 + kl] = f2bf(t[kl][nl]);
    }
}

// ---------------------------------------------------------------------------
// bf16 MFMA projection GEMM: C = xb @ wT^T (+bias)*scale.
// q,k stored head-major [bh][s][d]; v stored TRANSPOSED [bh][d][s].
// Round-10: BK 64 -> 32, STILL double-buffered. Mechanism (m132 vs m97
// controlled A/B in the catalog): the 64 KB-LDS K-loop config loses ~40% to
// occupancy (2 blocks/CU); BK=32-dbuf keeps the depth-1 pipeline (one
// barrier per step, next-step DMA issued before compute) at a 32 KB LDS
// footprint -> 3+ blocks/CU -> wave-level TLP (m114) hides the drain.
// Same total staging bytes; swizzle re-derived for 4-chunk rows.
// ---------------------------------------------------------------------------
__global__ __launch_bounds__(256) void proj_mfma_kernel(
    const short* __restrict__ xb, const short* __restrict__ wT,
    const float* __restrict__ bq, const float* __restrict__ bk,
    const float* __restrict__ bv, bf16* __restrict__ qkv)
{
    __shared__ short Ash[2][128 * 32];
    __shared__ short Bsh[2][128 * 32];

    // --- XCD-aware bijective remap (nwg = 12*128 = 1536, 1536 % 8 == 0) ---
    const int nwg  = gridDim.x * gridDim.y;          // 1536
    const int orig = blockIdx.y * gridDim.x + blockIdx.x;
    const int wid  = (orig & 7) * (nwg >> 3) + (orig >> 3);
    const int bx   = wid % 12;
    const int by   = wid / 12;

    const int widx = bx >> 2;
    const int col0 = (bx & 3) * 128;
    const int row0 = by * 128;
    const int tid  = threadIdx.x;
    const int w    = tid >> 6;
    const int lane = tid & 63;
    const int col  = lane & 15;
    const int kg   = lane >> 4;

    const float* bias = widx == 0 ? bq : (widx == 1 ? bk : bv);
    const float scale = widx == 0 ? QSCALE : 1.0f;
    const short* wbase = wT + (size_t)widx * D_MODEL * D_MODEL;

    const f32x4 zero4 = {0.f, 0.f, 0.f, 0.f};
    f32x4 acc[4][4];
#pragma unroll
    for (int i = 0; i < 4; ++i)
#pragma unroll
        for (int j = 0; j < 4; ++j) acc[i][j] = zero4;

    const int wm0 = (w >> 1) * 64;
    const int wn0 = (w & 1) * 64;

    // staging (BK=32): 128 rows x 4 chunks of 8 shorts per array = 512
    // chunks; 2 per thread per array. Physical slot p = (kc+((m>>1)&3))&3
    // (2-way bank aliasing on read = free, m136). Wave-uniform LDS base +
    // per-lane pre-swizzled global source (m173 pattern).
    auto stage = [&](int buf, int kb) {
#pragma unroll
        for (int half = 0; half < 2; ++half) {
            const int Lb = half * 256 + w * 64;      // wave-uniform chunk base
            const int L  = Lb + lane;
            const int mm = L >> 2;
            const int kc = ((L & 3) - ((mm >> 1) & 3)) & 3;
            const int ko = kb + kc * 8;
            gload_lds16(&Ash[buf][Lb * 8],
                        xb + (size_t)(row0 + mm) * D_MODEL + ko);
            gload_lds16(&Bsh[buf][Lb * 8],
                        wbase + (size_t)(col0 + mm) * D_MODEL + ko);
        }
    };

    // prologue: stage K-step 0 into buffer 0
    stage(0, 0);

    const int NSTEP = D_MODEL / 32;                  // 16
    for (int it = 0; it < NSTEP; ++it) {
        __syncthreads();   // drains buf[it&1]'s DMA (issued last iteration);
                           // also orders prev compute of buf[(it+1)&1]

        if (it + 1 < NSTEP) stage((it + 1) & 1, (it + 1) * 32);

        const short* Ab = Ash[it & 1];
        const short* Bb = Bsh[it & 1];

        short8 af[4], bfr[4];
#pragma unroll
        for (int mt = 0; mt < 4; ++mt) {
            const int m = wm0 + mt * 16 + col;
            const int c = m * 4 + ((kg + ((m >> 1) & 3)) & 3);
            af[mt] = *(const short8*)(Ab + (size_t)c * 8);
        }
#pragma unroll
        for (int nt = 0; nt < 4; ++nt) {
            const int n = wn0 + nt * 16 + col;
            const int c = n * 4 + ((kg + ((n >> 1) & 3)) & 3);
            bfr[nt] = *(const short8*)(Bb + (size_t)c * 8);
        }
#pragma unroll
        for (int mt = 0; mt < 4; ++mt)
#pragma unroll
            for (int nt = 0; nt < 4; ++nt)
                acc[mt][nt] = __builtin_amdgcn_mfma_f32_16x16x32_bf16(
                    af[mt], bfr[nt], acc[mt][nt], 0, 0, 0);
        // no trailing barrier: next iteration's top barrier covers reuse
    }

    bf16* dst = qkv + (size_t)widx * (NB * NH * S_LEN * HD);
#pragma unroll
    for (int nt = 0; nt < 4; ++nt) {
        const int n = col0 + wn0 + nt * 16 + col;
        const float bias_v = bias[n];
        const int h = n >> 6, d = n & 63;
#pragma unroll
        for (int mt = 0; mt < 4; ++mt) {
            const int m0 = row0 + wm0 + mt * 16 + kg * 4;
            const int b = m0 >> 13, s0 = m0 & (S_LEN - 1);
            if (widx == 2) {
                short4 pk;
                pk.x = f2bf(acc[mt][nt][0] + bias_v);
                pk.y = f2bf(acc[mt][nt][1] + bias_v);
                pk.z = f2bf(acc[mt][nt][2] + bias_v);
                pk.w = f2bf(acc[mt][nt][3] + bias_v);
                *(short4*)&dst[(((size_t)(b * NH + h)) * HD + d) * S_LEN + s0] = pk;
            } else {
#pragma unroll
                for (int r = 0; r < 4; ++r)
                    dst[(((size_t)(b * NH + h)) * S_LEN + s0 + r) * HD + d] =
                        __float2bfloat16((acc[mt][nt][r] + bias_v) * scale);
            }
        }
    }
}

// ---------------------------------------------------------------------------
// Fallback fp32 projection (only if ws too small)
// ---------------------------------------------------------------------------
__global__ __launch_bounds__(256) void proj_kernel(
    const float* __restrict__ x, const float* __restrict__ Wm,
    const float* __restrict__ bias, bf16* __restrict__ dst, float scale,
    int transpose_v)
{
    __shared__ float As[16][64];
    __shared__ float Bs[16][64];
    const int tid  = threadIdx.x;
    const int row0 = blockIdx.y * 64;
    const int col0 = blockIdx.x * 64;
    const int ty = tid >> 4, tx = tid & 15;
    const int t4 = tid * 4;
    const int ai = t4 >> 4, aj = t4 & 15;
    const int bj = t4 >> 6, bi = t4 & 63;
    float acc[4][4] = {};
    for (int kb = 0; kb < D_MODEL; kb += 16) {
        float4 av = *(const float4*)(x  + (size_t)(row0 + ai) * D_MODEL + kb + aj);
        float4 bv = *(const float4*)(Wm + (size_t)(kb + bj)  * D_MODEL + col0 + bi);
        As[aj + 0][ai] = av.x; As[aj + 1][ai] = av.y;
        As[aj + 2][ai] = av.z; As[aj + 3][ai] = av.w;
        *(float4*)(&Bs[bj][bi]) = bv;
        __syncthreads();
#pragma unroll
        for (int k = 0; k < 16; ++k) {
            float a[4], b[4];
#pragma unroll
            for (int ii = 0; ii < 4; ++ii) a[ii] = As[k][ty * 4 + ii];
#pragma unroll
            for (int jj = 0; jj < 4; ++jj) b[jj] = Bs[k][tx * 4 + jj];
#pragma unroll
            for (int ii = 0; ii < 4; ++ii)
#pragma unroll
                for (int jj = 0; jj < 4; ++jj) acc[ii][jj] += a[ii] * b[jj];
        }
        __syncthreads();
    }
#pragma unroll
    for (int ii = 0; ii < 4; ++ii) {
        const int m = row0 + ty * 4 + ii;
        const int b = m >> 13, s = m & (S_LEN - 1);
#pragma unroll
        for (int jj = 0; jj < 4; ++jj) {
            const int n = col0 + tx * 4 + jj;
            const int h = n >> 6, d = n & 63;
            const float v = (acc[ii][jj] + bias[n]) * scale;
            if (transpose_v)
                dst[(((size_t)(b * NH + h)) * HD + d) * S_LEN + s] = __float2bfloat16(v);
            else
                dst[(((size_t)(b * NH + h)) * S_LEN + s) * HD + d] = __float2bfloat16(v);
        }
    }
}

// ---------------------------------------------------------------------------
// Flash sliding-window attention v12 (r8 verbatim -- best measured: ~50 us.
// Psh round-trip + 16x16x32 PV; native exp2; defer-max; tree reductions).
// ---------------------------------------------------------------------------
__global__ __launch_bounds__(512) void attn_mfma5_kernel(
    const bf16* __restrict__ qw, const bf16* __restrict__ kw,
    const bf16* __restrict__ vt, float* __restrict__ out)
{
    __shared__ __align__(16) short Ksh[2][4096];     // [key][d] swizzled, 2x8KB
    __shared__ __align__(16) short Vsh[2][4096];     // [d][key] swizzled, 2x8KB
    __shared__ __align__(16) short Psh[8][16][72];   // per-wave [q][key], 18.4KB

    // --- XCD-aware bijective remap (nwg = 16*64 = 1024, 1024 % 8 == 0) ---
    const int orig = blockIdx.y * gridDim.x + blockIdx.x;
    const int wf   = (orig & 7) * 128 + (orig >> 3);
    const int bh   = wf >> 6;
    const int qt0  = (wf & 63) * 128;

    const int tid  = threadIdx.x;
    const int w    = tid >> 6;              // 0..7
    const int lane = tid & 63;
    const int col  = lane & 15;
    const int kg   = lane >> 4;
    const int q0   = qt0 + w * 16;
    const int q    = q0 + col;
    const size_t base = (size_t)bh * S_LEN * HD;

    const short* qg  = (const short*)qw;
    const short* kgp = (const short*)kw;
    const short* vgp = (const short*)vt;

    const int kt_lo = qt0 - WIN < 0 ? 0 : qt0 - WIN;
    const int kt_hi0 = qt0 + WIN + 64;      // covers q up to qt0+127
    const int kt_hi = kt_hi0 > S_LEN - 64 ? S_LEN - 64 : kt_hi0;
    const int NT    = ((kt_hi - kt_lo) >> 6) + 1;

    // staging: 512 chunks per array per tile, 1 per thread, XOR swizzle
    const int r0 = tid >> 3, c0 = (tid & 7) ^ (r0 & 7);
    const int ldsb = w * 64 * 8;            // wave-uniform chunk base (shorts)

    // Q B-frag: B[n=q][k=d]
    const short* qptr = qg + base + (size_t)q * HD + kg * 8;
    const short8 qB0 = *(const short8*)(qptr);
    const short8 qB1 = *(const short8*)(qptr + 32);

    const f32x4 zero4 = {0.f, 0.f, 0.f, 0.f};
    f32x4 Oacc[4] = {zero4, zero4, zero4, zero4};
    float m = -1e30f, l = 0.f;

    const int x7 = col & 7;

    // prologue: stage tile 0 into buffer 0
    gload_lds16(&Ksh[0][ldsb], kgp + base + (size_t)(kt_lo + r0) * HD + c0 * 8);
    gload_lds16(&Vsh[0][ldsb], vgp + base + (size_t)r0 * S_LEN + kt_lo + c0 * 8);

    for (int i = 0; i < NT; ++i) {
        __syncthreads();   // drains tile i's DMA (issued previous iteration)

        if (i + 1 < NT) {  // issue DMA for tile i+1 -> overlaps compute below
            const int ktn = kt_lo + 64 * (i + 1);
            const int nb = (i + 1) & 1;
            gload_lds16(&Ksh[nb][ldsb], kgp + base + (size_t)(ktn + r0) * HD + c0 * 8);
            gload_lds16(&Vsh[nb][ldsb], vgp + base + (size_t)r0 * S_LEN + ktn + c0 * 8);
        }

        const int kt = kt_lo + 64 * i;
        const short* Kb = Ksh[i & 1];
        const short* Vb = Vsh[i & 1];

        // ---- S^T = K . Q^T : A[m=key][k=d] from swizzled LDS ----
        f32x4 sc[4];
        __builtin_amdgcn_s_setprio(1);
#pragma unroll
        for (int t = 0; t < 4; ++t) {
            const int key = 16 * t + col;
            const short8 kA0 = *(const short8*)(Kb + (size_t)(key * 8 + (kg ^ x7)) * 8);
            const short8 kA1 = *(const short8*)(Kb + (size_t)(key * 8 + ((kg + 4) ^ x7)) * 8);
            f32x4 a = zero4;
            a = __builtin_amdgcn_mfma_f32_16x16x32_bf16(kA0, qB0, a, 0, 0, 0);
            a = __builtin_amdgcn_mfma_f32_16x16x32_bf16(kA1, qB1, a, 0, 0, 0);
            sc[t] = a;                     // sc[t][r] = S[kt+16t+4kg+r][q] (log2 units)
        }
        __builtin_amdgcn_s_setprio(0);

        // per-wave masking: tile fully valid iff kt >= q0+15-WIN && kt+63 <= q0+WIN
        const bool need_mask = (kt < q0 + 15 - WIN) || (kt + 63 > q0 + WIN);
        if (need_mask) {
#pragma unroll
            for (int t = 0; t < 4; ++t)
#pragma unroll
                for (int r = 0; r < 4; ++r) {
                    const int j = kt + 16 * t + kg * 4 + r;
                    if (j < q - WIN || j > q + WIN) sc[t][r] = -1e30f;
                }
        }

        // ---- tile max (tree) + cross-kg reduce ----
        float tm0 = fmaxf(fmaxf(sc[0][0], sc[0][1]), fmaxf(sc[0][2], sc[0][3]));
        float tm1 = fmaxf(fmaxf(sc[1][0], sc[1][1]), fmaxf(sc[1][2], sc[1][3]));
        float tm2 = fmaxf(fmaxf(sc[2][0], sc[2][1]), fmaxf(sc[2][2], sc[2][3]));
        float tm3 = fmaxf(fmaxf(sc[3][0], sc[3][1]), fmaxf(sc[3][2], sc[3][3]));
        float tmax = fmaxf(fmaxf(tm0, tm1), fmaxf(tm2, tm3));
        tmax = fmaxf(tmax, __shfl_xor(tmax, 16));
        tmax = fmaxf(tmax, __shfl_xor(tmax, 32));

        // ---- T13 defer-max: rescale only if some column grew by >8 ----
        if (__any(tmax > m + 8.f)) {
            const float mnew = fmaxf(m, tmax);
            const float alpha = EXP2N(m - mnew);   // 0 on first tile (m=-1e30)
            m = mnew;
#pragma unroll
            for (int dt = 0; dt < 4; ++dt)
#pragma unroll
                for (int r = 0; r < 4; ++r) Oacc[dt][r] *= alpha;
            l *= alpha;
        }

        // ---- p = 2^(sc - m); masked entries (-1e30) underflow to 0 ----
        float p[4][4];
#pragma unroll
        for (int t = 0; t < 4; ++t)
#pragma unroll
            for (int r = 0; r < 4; ++r) p[t][r] = EXP2N(sc[t][r] - m);

        float r0s = (p[0][0] + p[0][1]) + (p[0][2] + p[0][3]);
        float r1s = (p[1][0] + p[1][1]) + (p[1][2] + p[1][3]);
        float r2s = (p[2][0] + p[2][1]) + (p[2][2] + p[2][3]);
        float r3s = (p[3][0] + p[3][1]) + (p[3][2] + p[3][3]);
        float rs = (r0s + r1s) + (r2s + r3s);
        rs += __shfl_xor(rs, 16);
        rs += __shfl_xor(rs, 32);
        l += rs;

        // ---- P -> per-wave LDS (4x b64), read back as B-frags ----
#pragma unroll
        for (int t = 0; t < 4; ++t) {
            short4 pk;
            pk.x = f2bf(p[t][0]); pk.y = f2bf(p[t][1]);
            pk.z = f2bf(p[t][2]); pk.w = f2bf(p[t][3]);
            *(short4*)&Psh[w][col][16 * t + 4 * kg] = pk;
        }

        const short* pp = &Psh[w][col][kg * 8];   // same-wave RAW: in-order DS
        const short8 pB0 = *(const short8*)(pp);
        const short8 pB1 = *(const short8*)(pp + 32);

        // ---- O^T += V^T . P^T : A[m=d][k=key] from swizzled LDS ----
        __builtin_amdgcn_s_setprio(1);
#pragma unroll
        for (int dt = 0; dt < 4; ++dt) {
            const int d = dt * 16 + col;
            const short8 vA0 = *(const short8*)(Vb + (size_t)(d * 8 + (kg ^ x7)) * 8);
            const short8 vA1 = *(const short8*)(Vb + (size_t)(d * 8 + ((kg + 4) ^ x7)) * 8);
            Oacc[dt] = __builtin_amdgcn_mfma_f32_16x16x32_bf16(vA0, pB0, Oacc[dt], 0, 0, 0);
            Oacc[dt] = __builtin_amdgcn_mfma_f32_16x16x32_bf16(vA1, pB1, Oacc[dt], 0, 0, 0);
        }
        __builtin_amdgcn_s_setprio(0);
    }

    // ---- epilogue: coalesced float4 stores ----
    const float inv = 1.0f / l;
    const int b = bh >> 3, h = bh & 7;
    float* op = out + ((size_t)(b * S_LEN + q)) * D_MODEL + h * HD + kg * 4;
#pragma unroll
    for (int dt = 0; dt < 4; ++dt) {
        float4 o;
        o.x = Oacc[dt][0] * inv; o.y = Oacc[dt][1] * inv;
        o.z = Oacc[dt][2] * inv; o.w = Oacc[dt][3] * inv;
        *(float4*)(op + dt * 16) = o;
    }
}

// ---------------------------------------------------------------------------
extern "C" void kernel_launch(void* const* d_in, const int* in_sizes, int n_in,
                              void* d_out, int out_size, void* d_ws, size_t ws_size,
                              hipStream_t stream)
{
    const float* x  = (const float*)d_in[0];
    const float* Wq = (const float*)d_in[1];
    const float* bq = (const float*)d_in[2];
    const float* Wk = (const float*)d_in[3];
    const float* bk = (const float*)d_in[4];
    const float* Wv = (const float*)d_in[5];
    const float* bv = (const float*)d_in[6];
    float* out = (float*)d_out;

    const size_t n_elem = (size_t)NB * NH * S_LEN * HD;
    bf16* qw = (bf16*)d_ws;
    bf16* kw = qw + n_elem;
    bf16* vw = kw + n_elem;        // v TRANSPOSED: [bh][d][s]
    short* xb = (short*)(vw + n_elem);
    short* wT = xb + (size_t)NB * S_LEN * D_MODEL;

    const size_t need = (3 * n_elem + (size_t)NB * S_LEN * D_MODEL +
                         3 * (size_t)D_MODEL * D_MODEL) * sizeof(short);

    if (ws_size >= need) {
        convert_x_kernel<<<2048, 256, 0, stream>>>(x, xb);
        dim3 wgrid(D_MODEL / 32, D_MODEL / 32, 3);
        convert_wT_kernel<<<wgrid, 256, 0, stream>>>(Wq, Wk, Wv, wT);
        dim3 ggrid(12, (NB * S_LEN) / 128);
        proj_mfma_kernel<<<ggrid, 256, 0, stream>>>(xb, wT, bq, bk, bv, qw);
    } else {
        dim3 pgrid(D_MODEL / 64, (NB * S_LEN) / 64);
        proj_kernel<<<pgrid, 256, 0, stream>>>(x, Wq, bq, qw, QSCALE, 0);
        proj_kernel<<<pgrid, 256, 0, stream>>>(x, Wk, bk, kw, 1.0f, 0);
        proj_kernel<<<pgrid, 256, 0, stream>>>(x, Wv, bv, vw, 1.0f, 1);
    }

    dim3 agrid(NB * NH, S_LEN / 128);
    attn_mfma5_kernel<<<agrid, 512, 0, stream>>>(qw, kw, vw, out);
}